// Round 7
// baseline (723.288 us; speedup 1.0000x reference)
//
#include <hip/hip_runtime.h>
#include <hip/hip_bf16.h>

#define HIDDEN 768
#define MLPH   3072
#define HEADS  12
#define HD     64
#define SEQ    1024
#define BATCH  16
#define MTOT   (BATCH*SEQ)   // 16384

typedef __attribute__((ext_vector_type(8))) short  short8;
typedef __attribute__((ext_vector_type(4))) short  bfs4;
typedef __attribute__((ext_vector_type(8))) __bf16 bf16x8;
typedef __attribute__((ext_vector_type(4))) float  floatx4;

#define CL2 0.18033688011112042f   // 0.125 * log2(e): QK scale folded to exp2 domain

__device__ inline short f2bf(float f) {
  __hip_bfloat16 h = __float2bfloat16(f);
  return *reinterpret_cast<short*>(&h);
}

__device__ inline floatx4 mfma_bf16(short8 a, short8 b, floatx4 c) {
  return __builtin_amdgcn_mfma_f32_16x16x32_bf16(
      __builtin_bit_cast(bf16x8, a), __builtin_bit_cast(bf16x8, b), c, 0, 0, 0);
}

__device__ inline void gl_lds16(const short* g, short* l) {
  __builtin_amdgcn_global_load_lds(
      (const __attribute__((address_space(1))) unsigned int*)g,
      (__attribute__((address_space(3))) unsigned int*)l, 16, 0, 0);
}

// tanh-form GELU in exp2 domain (max |err| vs exact-erf GELU ~3e-4)
__device__ inline float gelu_f(float x) {
  float u = x * (2.3022089f + 0.1029483f * x * x);
  float e = exp2f(u);
  return x - x * __builtin_amdgcn_rcpf(1.0f + e);
}

// ---------------- weight conversion ----------------
// direct bf16 casts (coalesced)
__global__ __launch_bounds__(256) void conv_direct(
    const float* __restrict__ wq, const float* __restrict__ wk,
    const float* __restrict__ wv, const float* __restrict__ wo,
    short* __restrict__ wqkvb, short* __restrict__ wob)
{
  int i = blockIdx.x * 256 + threadIdx.x;
  const int HH = HIDDEN * HIDDEN;
  wqkvb[i]        = f2bf(wq[i]);
  wqkvb[HH + i]   = f2bf(wk[i]);
  wqkvb[2*HH + i] = f2bf(wv[i]);
  wob[i]          = f2bf(wo[i]);
}

// LDS-tiled transpose: out[c][r] = (bf16)in[r][c].  grid (C/32, R/32)
__global__ __launch_bounds__(256) void transpose_bf16(
    const float* __restrict__ in, short* __restrict__ out, int R, int C)
{
  __shared__ float tile[32][33];
  int c0 = blockIdx.x * 32, r0 = blockIdx.y * 32;
  int x = threadIdx.x & 31, y0 = threadIdx.x >> 5;
#pragma unroll
  for (int i = 0; i < 4; ++i) {
    int y = y0 + i * 8;
    tile[y][x] = in[(size_t)(r0 + y) * C + c0 + x];
  }
  __syncthreads();
#pragma unroll
  for (int i = 0; i < 4; ++i) {
    int y = y0 + i * 8;
    out[(size_t)(c0 + y) * R + r0 + x] = f2bf(tile[x][y]);
  }
}

// ---------------- layernorm (fp32 in, bf16 out) ----------------
__global__ __launch_bounds__(256) void ln_kernel(
    const float* __restrict__ x, const float* __restrict__ g,
    const float* __restrict__ b, short* __restrict__ out)
{
  int row = blockIdx.x;
  const float* xr = x + (size_t)row * HIDDEN;
  int t = threadIdx.x;
  float v0 = xr[t], v1 = xr[t + 256], v2 = xr[t + 512];
  float s  = v0 + v1 + v2;
  float s2 = v0*v0 + v1*v1 + v2*v2;
  for (int off = 32; off > 0; off >>= 1) {
    s  += __shfl_down(s, off);
    s2 += __shfl_down(s2, off);
  }
  __shared__ float red[8];
  __shared__ float stats[2];
  int wave = t >> 6;
  if ((t & 63) == 0) { red[wave] = s; red[4 + wave] = s2; }
  __syncthreads();
  if (t == 0) {
    float S  = red[0] + red[1] + red[2] + red[3];
    float S2 = red[4] + red[5] + red[6] + red[7];
    float mu  = S * (1.0f / HIDDEN);
    float var = S2 * (1.0f / HIDDEN) - mu * mu;
    stats[0] = mu;
    stats[1] = rsqrtf(var + 1e-5f);
  }
  __syncthreads();
  float mu = stats[0], rs = stats[1];
  short* orow = out + (size_t)row * HIDDEN;
  orow[t]       = f2bf((v0 - mu) * rs * g[t]       + b[t]);
  orow[t + 256] = f2bf((v1 - mu) * rs * g[t + 256] + b[t + 256]);
  orow[t + 512] = f2bf((v2 - mu) * rs * g[t + 512] + b[t + 512]);
}

// ---------------- BT-GEMM: C[M,N] = A[M,K] * B[N,K]^T ----------------
// Transposed accumulate: mfma(b, a) puts 4 CONSECUTIVE C-columns per lane
// (quad*4+r) at row lc -> float4/short4 epilogue loads & stores.
template<int OUTMODE /*0=f32,1=bf16*/, bool BIAS, bool GELU_E, bool RES,
         bool SCALEQ = false>
__global__ __launch_bounds__(256) void gemm_bt(
    const short* __restrict__ A, const short* __restrict__ B,
    const float* __restrict__ bias, const float* __restrict__ res,
    void* __restrict__ out, int M, int N, int K)
{
  __shared__ alignas(16) short As[128 * 32];
  __shared__ alignas(16) short Bs[128 * 32];
  int tid = threadIdx.x;
  int lane = tid & 63, wave = tid >> 6;
  int m0 = blockIdx.y * 128, n0 = blockIdx.x * 128;
  int wm = (wave >> 1) * 64, wn = (wave & 1) * 64;

  floatx4 acc[4][4];
#pragma unroll
  for (int i = 0; i < 4; ++i)
#pragma unroll
    for (int j = 0; j < 4; ++j) acc[i][j] = floatx4{0.f, 0.f, 0.f, 0.f};

  int lrow = lane >> 2;   // 0..15
  int lcb  = lane & 3;    // 0..3
  int kq   = lane >> 4;   // 0..3
  int lc   = lane & 15;

  for (int k0 = 0; k0 < K; k0 += 32) {
#pragma unroll
    for (int t = 0; t < 2; ++t) {
      int r  = t * 64 + wave * 16 + lrow;          // local row 0..127
      int kb = lcb ^ ((r >> 1) & 3);               // swizzled 16B block
      const short* ga = A + (size_t)(m0 + r) * K + k0 + kb * 8;
      const short* gb = B + (size_t)(n0 + r) * K + k0 + kb * 8;
      gl_lds16(ga, &As[(t * 64 + wave * 16) * 32]);
      gl_lds16(gb, &Bs[(t * 64 + wave * 16) * 32]);
    }
    __syncthreads();
    short8 af[4], bfr[4];
#pragma unroll
    for (int i = 0; i < 4; ++i) {
      int r = wm + i * 16 + lc;
      int c = kq ^ ((r >> 1) & 3);
      af[i] = *(const short8*)&As[r * 32 + c * 8];
    }
#pragma unroll
    for (int j = 0; j < 4; ++j) {
      int r = wn + j * 16 + lc;
      int c = kq ^ ((r >> 1) & 3);
      bfr[j] = *(const short8*)&Bs[r * 32 + c * 8];
    }
#pragma unroll
    for (int i = 0; i < 4; ++i)
#pragma unroll
      for (int j = 0; j < 4; ++j)
        acc[i][j] = mfma_bf16(bfr[j], af[i], acc[i][j]);   // swapped operands
    __syncthreads();
  }

  // epilogue (transposed layout): row = wm+i*16+lc, cols = wn+j*16+quad*4 .. +3
#pragma unroll
  for (int i = 0; i < 4; ++i) {
    int row = m0 + wm + i * 16 + lc;
#pragma unroll
    for (int j = 0; j < 4; ++j) {
      int colb = n0 + wn + j * 16 + kq * 4;
      floatx4 v = acc[i][j];
      if (BIAS)   v += *(const floatx4*)&bias[colb];
      if (GELU_E) {
#pragma unroll
        for (int r = 0; r < 4; ++r) v[r] = gelu_f(v[r]);
      }
      if (RES)    v += *(const floatx4*)&res[(size_t)row * N + colb];
      if (SCALEQ && colb < HIDDEN) v *= CL2;
      if (OUTMODE == 1) {
        bfs4 sv;
#pragma unroll
        for (int r = 0; r < 4; ++r) sv[r] = f2bf(v[r]);
        *(bfs4*)&((short*)out)[(size_t)row * N + colb] = sv;
      } else {
        *(floatx4*)&((float*)out)[(size_t)row * N + colb] = v;
      }
    }
  }
}

// ---------------- flash attention v3 (no online-max, deferred l) ----------
__global__ __launch_bounds__(256) void attn_kernel(
    const short* __restrict__ qkv, short* __restrict__ out)
{
  int qt = blockIdx.x;   // 0..15
  int h  = blockIdx.y;   // 0..11
  int b  = blockIdx.z;   // batch within chunk
  int tid = threadIdx.x, lane = tid & 63, wave = tid >> 6;
  int quad = lane >> 4, lc = lane & 15;

  __shared__ alignas(16) short Qs[2 * 64 * 32];
  __shared__ alignas(16) short Ks[2 * 64 * 32];
  __shared__ alignas(16) unsigned int Vt[64 * 32];
  __shared__ alignas(16) short Ps[4][16 * 64];

  const int LDQ = 3 * HIDDEN;  // 2304
  const short* qb = qkv + (size_t)(b * SEQ) * LDQ + h * HD;
  const short* kb = qb + HIDDEN;
  const short* vb = qb + 2 * HIDDEN;

  // ---- stage Q (once): swizzled half-tiles ----
  {
    int r_l = lane >> 2, lcb = lane & 3;
    int kblk = lcb ^ ((r_l >> 1) & 3);
#pragma unroll
    for (int t = 0; t < 2; ++t) {
      const short* g = qb + (size_t)(qt * 64 + wave * 16 + r_l) * LDQ + t * 32 + kblk * 8;
      gl_lds16(g, &Qs[t * 2048 + (wave * 16) * 32]);
    }
  }
  __syncthreads();

  // hoisted Q fragments (A-operand, row = wave*16+lc)
  short8 aq[2];
#pragma unroll
  for (int ks = 0; ks < 2; ++ks) {
    int pos = quad ^ ((lc >> 1) & 3);
    aq[ks] = *(const short8*)&Qs[ks * 2048 + (wave * 16 + lc) * 32 + pos * 8];
  }

  floatx4 oacc[4];
#pragma unroll
  for (int n2 = 0; n2 < 4; ++n2) oacc[n2] = floatx4{0.f, 0.f, 0.f, 0.f};
  float l_r[4] = {0.f, 0.f, 0.f, 0.f};   // lane-local partial row sums

  // V staging indices
  int rt = tid >> 3;        // 0..31 (row pair)
  int ct = tid & 7;         // col group of 8

  for (int kt = 0; kt < 16; ++kt) {
    // ---- stage K (swizzled halves) + V (transposed pair-packed) ----
    {
      int r_l = lane >> 2, lcb = lane & 3;
      int kblk = lcb ^ ((r_l >> 1) & 3);
#pragma unroll
      for (int t = 0; t < 2; ++t) {
        const short* g = kb + (size_t)(kt * 64 + wave * 16 + r_l) * LDQ + t * 32 + kblk * 8;
        gl_lds16(g, &Ks[t * 2048 + (wave * 16) * 32]);
      }
      const short* gv = vb + (size_t)(kt * 64 + 2 * rt) * LDQ + ct * 8;
      short8 v0 = *(const short8*)(gv);
      short8 v1 = *(const short8*)(gv + LDQ);
      int posv = (rt >> 2) ^ ct;
#pragma unroll
      for (int j = 0; j < 8; ++j) {
        unsigned int d = ((unsigned int)(unsigned short)v1[j] << 16) |
                          (unsigned int)(unsigned short)v0[j];
        Vt[(ct * 8 + j) * 32 + posv * 4 + (rt & 3)] = d;
      }
    }
    __syncthreads();

    // ---- S = Q K^T (wave's 16x64 strip); q pre-scaled -> exp2 domain ----
    floatx4 sacc[4];
#pragma unroll
    for (int n2 = 0; n2 < 4; ++n2) sacc[n2] = floatx4{0.f, 0.f, 0.f, 0.f};
#pragma unroll
    for (int ks = 0; ks < 2; ++ks) {
#pragma unroll
      for (int n2 = 0; n2 < 4; ++n2) {
        int pos = quad ^ ((lc >> 1) & 3);
        short8 bk = *(const short8*)&Ks[ks * 2048 + (n2 * 16 + lc) * 32 + pos * 8];
        sacc[n2] = mfma_bf16(aq[ks], bk, sacc[n2]);
      }
    }

    // ---- unnormalized exp2; accumulate lane-local l; P -> Ps swizzled ----
#pragma unroll
    for (int r = 0; r < 4; ++r) {
      int row = quad * 4 + r;
      float p0 = exp2f(sacc[0][r]);
      float p1 = exp2f(sacc[1][r]);
      float p2 = exp2f(sacc[2][r]);
      float p3 = exp2f(sacc[3][r]);
      l_r[r] += (p0 + p1) + (p2 + p3);
      float pv[4] = {p0, p1, p2, p3};
#pragma unroll
      for (int n2 = 0; n2 < 4; ++n2) {
        int tbw  = 2 * n2 + (lc >> 3);
        int posw = tbw ^ (row & 7);
        Ps[wave][row * 64 + posw * 8 + (lc & 7)] = f2bf(pv[n2]);
      }
    }
    __syncthreads();   // Ps visible (cross-lane) ; K reads complete

    // ---- O += P @ V ----
#pragma unroll
    for (int ks = 0; ks < 2; ++ks) {
      int posp = (ks * 4 + quad) ^ (lc & 7);
      short8 ap = *(const short8*)&Ps[wave][lc * 64 + posp * 8];
#pragma unroll
      for (int n2 = 0; n2 < 4; ++n2) {
        int c = n2 * 16 + lc;
        int posr = ((ks * 4 + quad) ^ ((c >> 3) & 7));
        short8 bv = *(const short8*)&Vt[c * 32 + posr * 4];
        oacc[n2] = mfma_bf16(ap, bv, oacc[n2]);
      }
    }
    __syncthreads();   // V/Ps reads done before next stage
  }

  // ---- epilogue: reduce l across the row's 16 lanes, divide, store ----
#pragma unroll
  for (int r = 0; r < 4; ++r) {
    float rs = l_r[r];
#pragma unroll
    for (int off = 1; off < 16; off <<= 1)
      rs += __shfl_xor(rs, off);
    float inv = 1.0f / rs;
    int row = b * SEQ + qt * 64 + wave * 16 + quad * 4 + r;
#pragma unroll
    for (int n2 = 0; n2 < 4; ++n2) {
      int col = h * HD + n2 * 16 + lc;
      out[(size_t)row * HIDDEN + col] = f2bf(oacc[n2][r] * inv);
    }
  }
}

// ---------------- launch ----------------
extern "C" void kernel_launch(void* const* d_in, const int* in_sizes, int n_in,
                              void* d_out, int out_size, void* d_ws, size_t ws_size,
                              hipStream_t stream) {
  const float* x    = (const float*)d_in[0];
  const float* ln1g = (const float*)d_in[1];
  const float* ln1b = (const float*)d_in[2];
  const float* wq   = (const float*)d_in[3];
  const float* wk   = (const float*)d_in[4];
  const float* wv   = (const float*)d_in[5];
  const float* wo   = (const float*)d_in[6];
  const float* bo   = (const float*)d_in[7];
  const float* ln2g = (const float*)d_in[8];
  const float* ln2b = (const float*)d_in[9];
  const float* w1   = (const float*)d_in[10];
  const float* b1   = (const float*)d_in[11];
  const float* w2   = (const float*)d_in[12];
  const float* b2   = (const float*)d_in[13];

  auto rup = [](size_t b) { return (b + 255) & ~(size_t)255; };
  const size_t wbytes = rup((size_t)3 * HIDDEN * HIDDEN * 2) +
                        rup((size_t)HIDDEN * HIDDEN * 2) +
                        rup((size_t)MLPH * HIDDEN * 2) +
                        rup((size_t)HIDDEN * MLPH * 2);

  int R = SEQ;
  const int cands[4] = {16384, 8192, 4096, 2048};
  for (int i = 0; i < 4; ++i) {
    size_t need = wbytes + rup((size_t)cands[i] * 1536) + rup((size_t)cands[i] * 6144);
    if (need <= ws_size) { R = cands[i]; break; }
  }

  char* ws = (char*)d_ws;
  size_t off = 0;
  auto alloc = [&](size_t bytes) {
    char* p = ws + off;
    off += (bytes + 255) & ~(size_t)255;
    return p;
  };
  short* wqkvb = (short*)alloc((size_t)3 * HIDDEN * HIDDEN * 2);
  short* wob   = (short*)alloc((size_t)HIDDEN * HIDDEN * 2);
  short* w1t   = (short*)alloc((size_t)MLPH * HIDDEN * 2);
  short* w2t   = (short*)alloc((size_t)HIDDEN * MLPH * 2);
  short* slotA = (short*)alloc((size_t)R * 1536);  // xn1 -> attn -> xn2
  short* bigR  = (short*)alloc((size_t)R * 6144);  // qkv  -> hdn

  conv_direct<<<HIDDEN * HIDDEN / 256, 256, 0, stream>>>(
      wq, wk, wv, wo, wqkvb, wob);
  transpose_bf16<<<dim3(MLPH / 32, HIDDEN / 32), 256, 0, stream>>>(
      w1, w1t, HIDDEN, MLPH);
  transpose_bf16<<<dim3(HIDDEN / 32, MLPH / 32), 256, 0, stream>>>(
      w2, w2t, MLPH, HIDDEN);

  const int nch = MTOT / R;
  for (int c = 0; c < nch; ++c) {
    const float* xc  = x + (size_t)c * R * HIDDEN;
    float*       x2c = (float*)d_out + (size_t)c * R * HIDDEN;

    ln_kernel<<<R, 256, 0, stream>>>(xc, ln1g, ln1b, slotA);
    gemm_bt<1, false, false, false, true>
        <<<dim3((3 * HIDDEN) / 128, R / 128), 256, 0, stream>>>(
        slotA, wqkvb, nullptr, nullptr, bigR, R, 3 * HIDDEN, HIDDEN);
    attn_kernel<<<dim3(SEQ / 64, HEADS, R / SEQ), 256, 0, stream>>>(bigR, slotA);
    gemm_bt<0, true, false, true>
        <<<dim3(HIDDEN / 128, R / 128), 256, 0, stream>>>(
        slotA, wob, bo, xc, x2c, R, HIDDEN, HIDDEN);
    ln_kernel<<<R, 256, 0, stream>>>(x2c, ln2g, ln2b, slotA);
    gemm_bt<1, true, true, false>
        <<<dim3(MLPH / 128, R / 128), 256, 0, stream>>>(
        slotA, w1t, b1, nullptr, bigR, R, MLPH, HIDDEN);
    gemm_bt<0, true, false, true>
        <<<dim3(HIDDEN / 128, R / 128), 256, 0, stream>>>(
        bigR, w2t, b2, x2c, x2c, R, HIDDEN, MLPH);
  }
}